// Round 1
// baseline (52519.012 us; speedup 1.0000x reference)
//
#include <hip/hip_runtime.h>
#include <hip/hip_cooperative_groups.h>
#include <cmath>

namespace cg = cooperative_groups;

// Model dims
#define TSTEPS 512
#define BB     128      // batch
#define HD     1024     // hidden
#define GD     4096     // 4*H
#define VD     128      // vocab
#define ED     128      // char emb
#define IE     32       // img emb
#define CD     160      // IE+ED

// ---------------- Fold kernels (run once per launch, trivial cost) ----------

// Wc[g][c] = sum_e W_ih[g][e] * W_proj[e][c];  gb[g] = b_ih+b_hh+W_ih@b_proj
__global__ void fold_wc_kernel(const float* __restrict__ W_ih,
                               const float* __restrict__ W_proj,
                               const float* __restrict__ b_proj,
                               const float* __restrict__ b_ih,
                               const float* __restrict__ b_hh,
                               float* __restrict__ Wc,
                               float* __restrict__ gb) {
    int idx = blockIdx.x * 256 + threadIdx.x;
    if (idx < GD * CD) {
        int g = idx / CD, c = idx - g * CD;
        const float* wr = W_ih + g * ED;
        float s = 0.f;
        #pragma unroll 8
        for (int e = 0; e < ED; ++e) s = fmaf(wr[e], W_proj[e * CD + c], s);
        Wc[idx] = s;
    }
    if (idx < GD) {
        const float* wr = W_ih + idx * ED;
        float s = b_ih[idx] + b_hh[idx];
        #pragma unroll 8
        for (int e = 0; e < ED; ++e) s = fmaf(wr[e], b_proj[e], s);
        gb[idx] = s;
    }
}

// Gimgb[b][g] = gb[g] + sum_{k<32} emb_img[img[b]][k] * Wc[g][k]
__global__ void fold_gimg_kernel(const float* __restrict__ emb_img,
                                 const int* __restrict__ input_img,
                                 const float* __restrict__ Wc,
                                 const float* __restrict__ gb,
                                 float* __restrict__ Gimgb) {
    int idx = blockIdx.x * 256 + threadIdx.x;   // BB*GD
    int b = idx >> 12, g = idx & (GD - 1);
    const float* e = emb_img + (size_t)input_img[b] * IE;
    const float* w = Wc + g * CD;
    float s = gb[g];
    #pragma unroll
    for (int k = 0; k < IE; ++k) s = fmaf(e[k], w[k], s);
    Gimgb[idx] = s;
}

// Gtok[v][g] = sum_{k<128} emb_char[v][k] * Wc[g][32+k]
__global__ void fold_gtok_kernel(const float* __restrict__ emb_char,
                                 const float* __restrict__ Wc,
                                 float* __restrict__ Gtok) {
    int idx = blockIdx.x * 256 + threadIdx.x;   // VD*GD
    int v = idx >> 12, g = idx & (GD - 1);
    const float* e = emb_char + v * ED;
    const float* w = Wc + g * CD + IE;
    float s = 0.f;
    #pragma unroll 8
    for (int k = 0; k < ED; ++k) s = fmaf(e[k], w[k], s);
    Gtok[idx] = s;
}

// Wpack[k4][col][0..3] = W_hh[col][4*k4 .. 4*k4+3]  (k-major transpose, float4)
// also zero both h buffers
__global__ void pack_whh_kernel(const float* __restrict__ W_hh,
                                float* __restrict__ Wpack,
                                float* __restrict__ hbuf) {
    int idx = blockIdx.x * 256 + threadIdx.x;   // GD*256
    if (idx < GD * 256) {
        int col = idx >> 8, k4 = idx & 255;
        float4 w = *reinterpret_cast<const float4*>(W_hh + (size_t)col * HD + k4 * 4);
        reinterpret_cast<float4*>(Wpack)[(size_t)k4 * GD + col] = w;
    }
    if (idx < 2 * BB * HD) hbuf[idx] = 0.f;
}

// ---------------- Persistent cooperative LSTM + fused logits ----------------
// grid = 256 blocks (8 batch-groups x 32 j-groups), 512 threads.
// thread -> (b_local = tid>>5 in 0..15, j = tid&31); owns 4 gates + c of (b,j).
__global__ __launch_bounds__(512) void lstm_fused(
    const float* __restrict__ Wpack,   // [256][4096][4]
    const float* __restrict__ Gimgb,   // [128][4096]
    const float* __restrict__ Gtok,    // [128][4096]
    const float* __restrict__ Wfc,     // [128][1024]
    const float* __restrict__ bfc,     // [128]
    const int*   __restrict__ x,       // [128][512]
    const int*   __restrict__ label,   // [128][512]
    float*       __restrict__ hbuf,    // [2][128][1024]
    float*       __restrict__ logits)  // [128][512][128]
{
    __shared__ float h_lds[16 * HD];   // 64 KiB: this bg's 16 h rows
    cg::grid_group grid = cg::this_grid();

    const int tid = threadIdx.x;
    const int bg = blockIdx.x >> 5;    // 0..7
    const int jg = blockIdx.x & 31;    // 0..31
    const int bl = tid >> 5;           // 0..15
    const int j  = tid & 31;
    const int b  = bg * 16 + bl;
    const int jglob = jg * 32 + j;

    // logits mapping: 64 dots (16 b x 4 v), 8 threads/dot split over k
    const int dot = tid >> 3, kc = tid & 7;
    const int lb  = dot >> 2;                 // 0..15
    const int v   = jg * 4 + (dot & 3);       // 0..127
    const float bfc_v = bfc[v];
    const float* __restrict__ wfc_row = Wfc + v * HD;

    float c_reg = 0.f;
    int cur = 0;

    for (int t = 0; t < TSTEPS; ++t) {
        // ---- stage h[cur] (state after step t-1) into LDS ----
        {
            const float4* src = reinterpret_cast<const float4*>(
                hbuf + (size_t)cur * (BB * HD) + (size_t)bg * 16 * HD);
            float4* dst = reinterpret_cast<float4*>(h_lds);
            #pragma unroll
            for (int i = 0; i < 8; ++i) dst[tid + i * 512] = src[tid + i * 512];
        }
        __syncthreads();

        // ---- logits for step t-1 (uses the same staged h) ----
        if (t > 0) {
            const float* hrow = h_lds + lb * HD;
            float s = 0.f;
            #pragma unroll 8
            for (int i = 0; i < 128; ++i) {
                int k = kc + (i << 3);
                s = fmaf(hrow[k], wfc_row[k], s);
            }
            s += __shfl_down(s, 4, 8);
            s += __shfl_down(s, 2, 8);
            s += __shfl_down(s, 1, 8);
            if (kc == 0)
                logits[(((size_t)(bg * 16 + lb)) * TSTEPS + (t - 1)) * VD + v] = s + bfc_v;
        }

        // ---- gates: a_g = gx(b,t) + h_{t-1} . W_hh[g*1024+jglob] ----
        const int tokid = (t == 0) ? x[b * TSTEPS] : label[b * TSTEPS + t - 1];
        const float* gi = Gimgb + (size_t)b * GD + jglob;
        const float* gt = Gtok + (size_t)tokid * GD + jglob;
        float a0 = gi[0]    + gt[0];
        float a1 = gi[1024] + gt[1024];
        float a2 = gi[2048] + gt[2048];
        float a3 = gi[3072] + gt[3072];

        const float*  hr = h_lds + bl * HD;
        const float4* wp = reinterpret_cast<const float4*>(Wpack) + jglob;
        #pragma unroll 4
        for (int k4 = 0; k4 < 256; ++k4) {
            float4 h4 = *reinterpret_cast<const float4*>(hr + k4 * 4);
            float4 w0 = wp[(size_t)k4 * GD + 0];
            float4 w1 = wp[(size_t)k4 * GD + 1024];
            float4 w2 = wp[(size_t)k4 * GD + 2048];
            float4 w3 = wp[(size_t)k4 * GD + 3072];
            a0 = fmaf(w0.x, h4.x, fmaf(w0.y, h4.y, fmaf(w0.z, h4.z, fmaf(w0.w, h4.w, a0))));
            a1 = fmaf(w1.x, h4.x, fmaf(w1.y, h4.y, fmaf(w1.z, h4.z, fmaf(w1.w, h4.w, a1))));
            a2 = fmaf(w2.x, h4.x, fmaf(w2.y, h4.y, fmaf(w2.z, h4.z, fmaf(w2.w, h4.w, a2))));
            a3 = fmaf(w3.x, h4.x, fmaf(w3.y, h4.y, fmaf(w3.z, h4.z, fmaf(w3.w, h4.w, a3))));
        }

        // torch gate order: i, f, g, o
        float ig = 1.f / (1.f + expf(-a0));
        float fg = 1.f / (1.f + expf(-a1));
        float gg = tanhf(a2);
        float og = 1.f / (1.f + expf(-a3));
        c_reg = fmaf(fg, c_reg, ig * gg);
        float hnew = og * tanhf(c_reg);

        hbuf[(size_t)(cur ^ 1) * (BB * HD) + (size_t)b * HD + jglob] = hnew;
        grid.sync();
        cur ^= 1;
    }

    // ---- final logits for t = 511 ----
    {
        const float4* src = reinterpret_cast<const float4*>(
            hbuf + (size_t)cur * (BB * HD) + (size_t)bg * 16 * HD);
        float4* dst = reinterpret_cast<float4*>(h_lds);
        #pragma unroll
        for (int i = 0; i < 8; ++i) dst[tid + i * 512] = src[tid + i * 512];
    }
    __syncthreads();
    {
        const float* hrow = h_lds + lb * HD;
        float s = 0.f;
        #pragma unroll 8
        for (int i = 0; i < 128; ++i) {
            int k = kc + (i << 3);
            s = fmaf(hrow[k], wfc_row[k], s);
        }
        s += __shfl_down(s, 4, 8);
        s += __shfl_down(s, 2, 8);
        s += __shfl_down(s, 1, 8);
        if (kc == 0)
            logits[(((size_t)(bg * 16 + lb)) * TSTEPS + (TSTEPS - 1)) * VD + v] = s + bfc_v;
    }
}

// ---------------- argmax (first-occurrence tie-break, preds as float) -------
__global__ void argmax_kernel(const float* __restrict__ logits,
                              float* __restrict__ preds) {
    int row = blockIdx.x * 4 + (threadIdx.x >> 6);   // 65536 rows
    int lane = threadIdx.x & 63;
    const float* r = logits + (size_t)row * VD;
    float v0 = r[lane * 2], v1 = r[lane * 2 + 1];
    float bv; int bi;
    if (v1 > v0) { bv = v1; bi = lane * 2 + 1; } else { bv = v0; bi = lane * 2; }
    #pragma unroll
    for (int d = 32; d >= 1; d >>= 1) {
        float ov = __shfl_down(bv, d);
        int   oi = __shfl_down(bi, d);
        if (ov > bv || (ov == bv && oi < bi)) { bv = ov; bi = oi; }
    }
    if (lane == 0) preds[row] = (float)bi;
}

// ---------------- launch ----------------------------------------------------
extern "C" void kernel_launch(void* const* d_in, const int* in_sizes, int n_in,
                              void* d_out, int out_size, void* d_ws, size_t ws_size,
                              hipStream_t stream) {
    const int*   input_img = (const int*)  d_in[0];
    const int*   x         = (const int*)  d_in[1];
    const int*   label     = (const int*)  d_in[2];
    const float* emb_img   = (const float*)d_in[3];
    const float* emb_char  = (const float*)d_in[4];
    const float* W_proj    = (const float*)d_in[5];
    const float* b_proj    = (const float*)d_in[6];
    const float* W_ih      = (const float*)d_in[7];
    const float* W_hh      = (const float*)d_in[8];
    const float* b_ih      = (const float*)d_in[9];
    const float* b_hh      = (const float*)d_in[10];
    const float* W_fc      = (const float*)d_in[11];
    const float* b_fc      = (const float*)d_in[12];

    float* ws     = (float*)d_ws;
    float* Wpack  = ws;                          // 4096*1024
    float* Wc     = Wpack + (size_t)GD * HD;     // 4096*160
    float* gb     = Wc + (size_t)GD * CD;        // 4096
    float* Gimgb  = gb + GD;                     // 128*4096
    float* Gtok   = Gimgb + (size_t)BB * GD;     // 128*4096
    float* hbuf   = Gtok + (size_t)VD * GD;      // 2*128*1024

    float* logits = (float*)d_out;               // 128*512*128
    float* preds  = logits + (size_t)BB * TSTEPS * VD;

    fold_wc_kernel  <<<(GD * CD + 255) / 256, 256, 0, stream>>>(W_ih, W_proj, b_proj, b_ih, b_hh, Wc, gb);
    fold_gimg_kernel<<<(BB * GD) / 256, 256, 0, stream>>>(emb_img, input_img, Wc, gb, Gimgb);
    fold_gtok_kernel<<<(VD * GD) / 256, 256, 0, stream>>>(emb_char, Wc, Gtok);
    pack_whh_kernel <<<(GD * 256) / 256, 256, 0, stream>>>(W_hh, Wpack, hbuf);

    void* args[] = { (void*)&Wpack, (void*)&Gimgb, (void*)&Gtok, (void*)&W_fc,
                     (void*)&b_fc, (void*)&x, (void*)&label, (void*)&hbuf, (void*)&logits };
    hipLaunchCooperativeKernel((void*)lstm_fused, dim3(256), dim3(512), args, 0, stream);

    argmax_kernel<<<(BB * TSTEPS) / 4, 256, 0, stream>>>(logits, preds);
}

// Round 2
// 27083.063 us; speedup vs baseline: 1.9392x; 1.9392x over previous
//
#include <hip/hip_runtime.h>
#include <hip/hip_cooperative_groups.h>
#include <cmath>

namespace cg = cooperative_groups;

// Model dims
#define TSTEPS 512
#define BB     128      // batch
#define HD     1024     // hidden
#define GD     4096     // 4*H
#define VD     128      // vocab
#define ED     128      // char emb
#define IE     32       // img emb
#define CD     160      // IE+ED

// ---------------- Fold kernels (run once per launch, trivial cost) ----------

// Wc[g][c] = sum_e W_ih[g][e] * W_proj[e][c];  gb[g] = b_ih+b_hh+W_ih@b_proj
__global__ void fold_wc_kernel(const float* __restrict__ W_ih,
                               const float* __restrict__ W_proj,
                               const float* __restrict__ b_proj,
                               const float* __restrict__ b_ih,
                               const float* __restrict__ b_hh,
                               float* __restrict__ Wc,
                               float* __restrict__ gb) {
    int idx = blockIdx.x * 256 + threadIdx.x;
    if (idx < GD * CD) {
        int g = idx / CD, c = idx - g * CD;
        const float* wr = W_ih + g * ED;
        float s = 0.f;
        #pragma unroll 8
        for (int e = 0; e < ED; ++e) s = fmaf(wr[e], W_proj[e * CD + c], s);
        Wc[idx] = s;
    }
    if (idx < GD) {
        const float* wr = W_ih + idx * ED;
        float s = b_ih[idx] + b_hh[idx];
        #pragma unroll 8
        for (int e = 0; e < ED; ++e) s = fmaf(wr[e], b_proj[e], s);
        gb[idx] = s;
    }
}

// Gimgb[b][g] = gb[g] + sum_{k<32} emb_img[img[b]][k] * Wc[g][k]
__global__ void fold_gimg_kernel(const float* __restrict__ emb_img,
                                 const int* __restrict__ input_img,
                                 const float* __restrict__ Wc,
                                 const float* __restrict__ gb,
                                 float* __restrict__ Gimgb) {
    int idx = blockIdx.x * 256 + threadIdx.x;   // BB*GD
    int b = idx >> 12, g = idx & (GD - 1);
    const float* e = emb_img + (size_t)input_img[b] * IE;
    const float* w = Wc + g * CD;
    float s = gb[g];
    #pragma unroll
    for (int k = 0; k < IE; ++k) s = fmaf(e[k], w[k], s);
    Gimgb[idx] = s;
}

// Gtok[v][g] = sum_{k<128} emb_char[v][k] * Wc[g][32+k]
__global__ void fold_gtok_kernel(const float* __restrict__ emb_char,
                                 const float* __restrict__ Wc,
                                 float* __restrict__ Gtok) {
    int idx = blockIdx.x * 256 + threadIdx.x;   // VD*GD
    int v = idx >> 12, g = idx & (GD - 1);
    const float* e = emb_char + v * ED;
    const float* w = Wc + g * CD + IE;
    float s = 0.f;
    #pragma unroll 8
    for (int k = 0; k < ED; ++k) s = fmaf(e[k], w[k], s);
    Gtok[idx] = s;
}

// W3 packing: lane-contiguous weight layout for the main kernel.
// f4 flat index = (((jb*16 + i)*4 + g)*16 + ks)*4 + jl
//   jb = col/4 (0..255), jl = col&3, i = 0..15, g = gate, ks = 0..15
//   covers k4 = i*16 + ks  (k = k4*4 + e)
// Per (jb,i,g) one wave load of 64 consecutive float4 = 1 KB, fully coalesced.
__global__ void pack_w3_kernel(const float* __restrict__ W_hh,
                               float* __restrict__ W3,
                               float* __restrict__ hbuf) {
    int idx = blockIdx.x * 256 + threadIdx.x;   // 1048576 float4 units
    int jl = idx & 3;
    int ks = (idx >> 2) & 15;
    int g  = (idx >> 6) & 3;
    int i  = (idx >> 8) & 15;
    int jb = idx >> 12;
    int row = g * HD + jb * 4 + jl;             // gate-major row of W_hh [4096][1024]
    int k4  = i * 16 + ks;
    reinterpret_cast<float4*>(W3)[idx] =
        reinterpret_cast<const float4*>(W_hh)[(size_t)row * 256 + k4];
    if (idx < 2 * BB * HD / 4)
        reinterpret_cast<float4*>(hbuf)[idx] = make_float4(0.f, 0.f, 0.f, 0.f);
}

// ---------------- Persistent cooperative LSTM + fused logits ----------------
// grid = 256 blocks x 1024 threads (1 block/CU, 16 waves/CU).
// Block (bg, jg): bg = 8 batch rows, jg = 64 gate-columns (x4 gates).
// XCD-aware: jg pairs pinned per XCD so each XCD's weight slice (2MB) is
// L2-resident. Wave w handles jb = jg*16+w (4 cols); lane = ks*4+jl:
// ks = 16-way k-split (64 k each), jl = col within jb.
// Thread: 32 accumulators (4 gates x 8 batch rows); k-partials combined by
// shfl_xor butterfly over lane bits 2..5; lane ks<8 owns activation of b=ks.
__global__ __launch_bounds__(1024, 4) void lstm_fused(
    const float* __restrict__ W3,      // packed, see pack_w3_kernel
    const float* __restrict__ Gimgb,   // [128][4096]
    const float* __restrict__ Gtok,    // [128][4096]
    const float* __restrict__ Wfc,     // [128][1024]
    const float* __restrict__ bfc,     // [128]
    const int*   __restrict__ x,       // [128][512]
    const int*   __restrict__ label,   // [128][512]
    float*       __restrict__ hbuf,    // [2][128][1024]
    float*       __restrict__ logits)  // [128][512][128]
{
    __shared__ float h_lds[8 * HD];    // 32 KiB: this bg's 8 h rows
    cg::grid_group grid = cg::this_grid();

    const int tid  = threadIdx.x;
    const int bid  = blockIdx.x;
    const int xcd  = bid & 7;
    const int slot = bid >> 3;         // 0..31
    const int jg   = xcd * 2 + (slot & 1);   // 0..15 (pinned per XCD)
    const int bg   = slot >> 1;              // 0..15
    const int w    = tid >> 6;               // wave 0..15 -> jb local
    const int lane = tid & 63;
    const int ks   = lane >> 2;              // 0..15 k-split
    const int jl   = lane & 3;
    const int jb   = jg * 16 + w;            // 0..255
    const int col  = jb * 4 + jl;            // 0..1023

    // logits mapping: 64 dots (8 b x 8 v) per block, 16 threads/dot over k
    const int dotid = tid >> 4, kc = tid & 15;
    const int lb    = dotid >> 3;            // 0..7 local b
    const int v     = jg * 8 + (dotid & 7);  // 0..127
    const float bfc_v = bfc[v];

    const float4* __restrict__ W3f4  = reinterpret_cast<const float4*>(W3);
    const float4* __restrict__ Wfcf4 = reinterpret_cast<const float4*>(Wfc);
    float4* h_ldsf4 = reinterpret_cast<float4*>(h_lds);

    const float4* __restrict__ wbase = W3f4 + (size_t)jb * 4096 + lane;

    const int b_own = bg * 8 + ks;     // valid when ks < 8

    float c_reg = 0.f;
    int cur = 0;

    for (int t = 0; t < TSTEPS; ++t) {
        // ---- stage h[cur] (state after step t-1) into LDS ----
        {
            const float4* src = reinterpret_cast<const float4*>(
                hbuf + (size_t)cur * (BB * HD) + (size_t)bg * 8 * HD);
            h_ldsf4[tid]        = src[tid];
            h_ldsf4[tid + 1024] = src[tid + 1024];
        }
        __syncthreads();

        // ---- logits for step t-1 (same staged h) ----
        if (t > 0) {
            const float4* hv = h_ldsf4 + lb * 256;
            const float4* wv = Wfcf4 + v * 256;
            float s = 0.f;
            #pragma unroll
            for (int m = 0; m < 16; ++m) {
                float4 h4 = hv[m * 16 + kc];
                float4 w4 = wv[m * 16 + kc];
                s = fmaf(h4.x, w4.x, fmaf(h4.y, w4.y,
                    fmaf(h4.z, w4.z, fmaf(h4.w, w4.w, s))));
            }
            s += __shfl_xor(s, 1); s += __shfl_xor(s, 2);
            s += __shfl_xor(s, 4); s += __shfl_xor(s, 8);
            if (kc == 0)
                logits[((size_t)(bg * 8 + lb) * TSTEPS + (t - 1)) * VD + v] = s + bfc_v;
        }

        // ---- main: partial gates over this lane's 64 k values ----
        float acc[4][8];
        #pragma unroll
        for (int g = 0; g < 4; ++g)
            #pragma unroll
            for (int b = 0; b < 8; ++b) acc[g][b] = 0.f;

        #pragma unroll 2
        for (int i = 0; i < 16; ++i) {
            float4 h4[8];
            #pragma unroll
            for (int b = 0; b < 8; ++b)
                h4[b] = h_ldsf4[b * 256 + i * 16 + ks];   // 2-way bank alias: free
            #pragma unroll
            for (int g = 0; g < 4; ++g) {
                float4 w4 = wbase[(i * 4 + g) * 64];      // 1KB contiguous per wave
                #pragma unroll
                for (int b = 0; b < 8; ++b)
                    acc[g][b] = fmaf(w4.x, h4[b].x, fmaf(w4.y, h4[b].y,
                                fmaf(w4.z, h4[b].z, fmaf(w4.w, h4[b].w, acc[g][b]))));
            }
        }

        // ---- combine k-split partials: butterfly over lane bits 2..5 ----
        #pragma unroll
        for (int g = 0; g < 4; ++g) {
            #pragma unroll
            for (int b = 0; b < 8; ++b) {
                float vs = acc[g][b];
                vs += __shfl_xor(vs, 4);
                vs += __shfl_xor(vs, 8);
                vs += __shfl_xor(vs, 16);
                vs += __shfl_xor(vs, 32);
                acc[g][b] = vs;
            }
        }

        // ---- activation: lane ks<8 owns batch row b=ks of column `col` ----
        if (ks < 8) {
            const int tok = (t == 0) ? x[b_own * TSTEPS]
                                     : label[b_own * TSTEPS + t - 1];
            const float* gi = Gimgb + (size_t)b_own * GD + col;
            const float* gt = Gtok + (size_t)tok * GD + col;
            float a0 = acc[0][ks] + gi[0]    + gt[0];
            float a1 = acc[1][ks] + gi[1024] + gt[1024];
            float a2 = acc[2][ks] + gi[2048] + gt[2048];
            float a3 = acc[3][ks] + gi[3072] + gt[3072];
            float ig = 1.f / (1.f + expf(-a0));
            float fg = 1.f / (1.f + expf(-a1));
            float gg = tanhf(a2);
            float og = 1.f / (1.f + expf(-a3));
            c_reg = fmaf(fg, c_reg, ig * gg);
            float hnew = og * tanhf(c_reg);
            hbuf[(size_t)(cur ^ 1) * (BB * HD) + (size_t)b_own * HD + col] = hnew;
        }
        grid.sync();
        cur ^= 1;
    }

    // ---- final logits for t = 511 ----
    {
        const float4* src = reinterpret_cast<const float4*>(
            hbuf + (size_t)cur * (BB * HD) + (size_t)bg * 8 * HD);
        h_ldsf4[tid]        = src[tid];
        h_ldsf4[tid + 1024] = src[tid + 1024];
    }
    __syncthreads();
    {
        const float4* hv = h_ldsf4 + lb * 256;
        const float4* wv = Wfcf4 + v * 256;
        float s = 0.f;
        #pragma unroll
        for (int m = 0; m < 16; ++m) {
            float4 h4 = hv[m * 16 + kc];
            float4 w4 = wv[m * 16 + kc];
            s = fmaf(h4.x, w4.x, fmaf(h4.y, w4.y,
                fmaf(h4.z, w4.z, fmaf(h4.w, w4.w, s))));
        }
        s += __shfl_xor(s, 1); s += __shfl_xor(s, 2);
        s += __shfl_xor(s, 4); s += __shfl_xor(s, 8);
        if (kc == 0)
            logits[((size_t)(bg * 8 + lb) * TSTEPS + (TSTEPS - 1)) * VD + v] = s + bfc_v;
    }
}

// ---------------- argmax (first-occurrence tie-break, preds as float) -------
__global__ void argmax_kernel(const float* __restrict__ logits,
                              float* __restrict__ preds) {
    int row = blockIdx.x * 4 + (threadIdx.x >> 6);   // 65536 rows
    int lane = threadIdx.x & 63;
    const float* r = logits + (size_t)row * VD;
    float v0 = r[lane * 2], v1 = r[lane * 2 + 1];
    float bv; int bi;
    if (v1 > v0) { bv = v1; bi = lane * 2 + 1; } else { bv = v0; bi = lane * 2; }
    #pragma unroll
    for (int d = 32; d >= 1; d >>= 1) {
        float ov = __shfl_down(bv, d);
        int   oi = __shfl_down(bi, d);
        if (ov > bv || (ov == bv && oi < bi)) { bv = ov; bi = oi; }
    }
    if (lane == 0) preds[row] = (float)bi;
}

// ---------------- launch ----------------------------------------------------
extern "C" void kernel_launch(void* const* d_in, const int* in_sizes, int n_in,
                              void* d_out, int out_size, void* d_ws, size_t ws_size,
                              hipStream_t stream) {
    const int*   input_img = (const int*)  d_in[0];
    const int*   x         = (const int*)  d_in[1];
    const int*   label     = (const int*)  d_in[2];
    const float* emb_img   = (const float*)d_in[3];
    const float* emb_char  = (const float*)d_in[4];
    const float* W_proj    = (const float*)d_in[5];
    const float* b_proj    = (const float*)d_in[6];
    const float* W_ih      = (const float*)d_in[7];
    const float* W_hh      = (const float*)d_in[8];
    const float* b_ih      = (const float*)d_in[9];
    const float* b_hh      = (const float*)d_in[10];
    const float* W_fc      = (const float*)d_in[11];
    const float* b_fc      = (const float*)d_in[12];

    float* ws     = (float*)d_ws;
    float* W3     = ws;                          // 4096*1024
    float* Wc     = W3 + (size_t)GD * HD;        // 4096*160
    float* gb     = Wc + (size_t)GD * CD;        // 4096
    float* Gimgb  = gb + GD;                     // 128*4096
    float* Gtok   = Gimgb + (size_t)BB * GD;     // 128*4096
    float* hbuf   = Gtok + (size_t)VD * GD;      // 2*128*1024

    float* logits = (float*)d_out;               // 128*512*128
    float* preds  = logits + (size_t)BB * TSTEPS * VD;

    fold_wc_kernel  <<<(GD * CD + 255) / 256, 256, 0, stream>>>(W_ih, W_proj, b_proj, b_ih, b_hh, Wc, gb);
    fold_gimg_kernel<<<(BB * GD) / 256, 256, 0, stream>>>(emb_img, input_img, Wc, gb, Gimgb);
    fold_gtok_kernel<<<(VD * GD) / 256, 256, 0, stream>>>(emb_char, Wc, Gtok);
    pack_w3_kernel  <<<(GD * HD / 4) / 256, 256, 0, stream>>>(W_hh, W3, hbuf);

    void* args[] = { (void*)&W3, (void*)&Gimgb, (void*)&Gtok, (void*)&W_fc,
                     (void*)&b_fc, (void*)&x, (void*)&label, (void*)&hbuf, (void*)&logits };
    hipLaunchCooperativeKernel((void*)lstm_fused, dim3(256), dim3(1024), args, 0, stream);

    argmax_kernel<<<(BB * TSTEPS) / 4, 256, 0, stream>>>(logits, preds);
}